// Round 1
// baseline (579.259 us; speedup 1.0000x reference)
//
#include <hip/hip_runtime.h>

// ---------------------------------------------------------------------------
// Spatial transformer: loc-net (conv7x7-BN-pool-relu, conv5x5-BN-pool-relu,
// conv1x1-BN-relu, avgpool, fc) -> theta -> affine grid -> bilinear sample.
// N=16384, x:[N,1,28,28] fp32. All BNs use batch stats -> global reductions.
// ---------------------------------------------------------------------------

static constexpr float kEPS = 1e-5f;

// ws float offsets
#define O_SUM1 0
#define O_SSQ1 8
#define O_SUM2 16
#define O_SSQ2 26
#define O_MOM  36      // 10 means + 55 upper-tri second moments of pool2
#define O_S1   104
#define O_T1   112
#define O_S2   120
#define O_T2   130
#define O_S3   140
#define O_T3   268
#define O_THETA 512            // 16384*6
#define O_POOL1 98816          // [N,8,11,11]  15,859,712 floats
#define O_CONV2 15958528       // [N,10,7,7]    8,028,160 floats
#define O_POOL2 23986688       // [N,10,3,3]    1,474,560 floats
// total ws use: 25,461,248 floats = ~101.9 MB

__global__ __launch_bounds__(256) void k_zero(float* __restrict__ ws){
  int i = blockIdx.x*256 + threadIdx.x;
  if (i < 512) ws[i] = 0.f;
}

// conv1 7x7 [N,1,28,28]->[N,8,22,22]. PASS0: accumulate BN stats.
// PASS1: BN affine + 2x2 maxpool + relu -> pool1 [N,8,11,11].
// thread <-> (n, c, p-half); conv rows computed in pairs (one pooled row).
template<int PASS>
__global__ __launch_bounds__(256) void k_conv1(const float* __restrict__ x,
                                               const float* __restrict__ w1,
                                               float* __restrict__ ws){
  const int tid = threadIdx.x;
  const int gid = blockIdx.x*256 + tid;
  const int ph = gid & 1;          // which half of the 11 pooled rows
  const int c  = (gid >> 1) & 7;
  const int n  = gid >> 4;
  const float* __restrict__ xs = x + n*784;
  float w[49];
  #pragma unroll
  for (int i=0;i<49;i++) w[i] = w1[c*49+i];
  float sbn = 0.f, tbn = 0.f;
  if (PASS==1){ sbn = ws[O_S1+c]; tbn = ws[O_T1+c]; }
  float sum=0.f, ssq=0.f;
  float* __restrict__ outp = ws + O_POOL1 + (n*8+c)*121;
  const int p0 = ph*6;
  const int p1 = ph ? 11 : 6;
  for (int p=p0; p<p1; p++){
    float a0[22], a1[22];
    #pragma unroll
    for (int i=0;i<22;i++){ a0[i]=0.f; a1[i]=0.f; }
    #pragma unroll
    for (int j=0;j<8;j++){            // input rows 2p..2p+7 feed conv rows 2p,2p+1
      float in[28];
      const float4* __restrict__ rp = (const float4*)(xs + (2*p+j)*28);
      #pragma unroll
      for (int q=0;q<7;q++){
        float4 v = rp[q];
        in[4*q]=v.x; in[4*q+1]=v.y; in[4*q+2]=v.z; in[4*q+3]=v.w;
      }
      if (j < 7){                     // ky = j for conv row 2p
        #pragma unroll
        for (int kx=0;kx<7;kx++){
          float wv = w[j*7+kx];
          #pragma unroll
          for (int xo=0;xo<22;xo++) a0[xo] = fmaf(wv, in[xo+kx], a0[xo]);
        }
      }
      if (j >= 1){                    // ky = j-1 for conv row 2p+1
        #pragma unroll
        for (int kx=0;kx<7;kx++){
          float wv = w[(j-1)*7+kx];
          #pragma unroll
          for (int xo=0;xo<22;xo++) a1[xo] = fmaf(wv, in[xo+kx], a1[xo]);
        }
      }
    }
    if (PASS==0){
      #pragma unroll
      for (int xo=0;xo<22;xo++){
        sum += a0[xo] + a1[xo];
        ssq = fmaf(a0[xo],a0[xo],ssq);
        ssq = fmaf(a1[xo],a1[xo],ssq);
      }
    } else {
      #pragma unroll
      for (int px=0;px<11;px++){
        float m4 = fmaxf(fmaxf(a0[2*px],a0[2*px+1]), fmaxf(a1[2*px],a1[2*px+1]));
        float n4 = fminf(fminf(a0[2*px],a0[2*px+1]), fminf(a1[2*px],a1[2*px+1]));
        float ext = (sbn >= 0.f) ? m4 : n4;  // maxpool after affine: sign-aware
        outp[p*11+px] = fmaxf(fmaf(sbn, ext, tbn), 0.f);
      }
    }
  }
  if (PASS==0){
    // lanes sharing c differ in bits {0,4,5} of lane id
    sum += __shfl_xor(sum,1);  ssq += __shfl_xor(ssq,1);
    sum += __shfl_xor(sum,16); ssq += __shfl_xor(ssq,16);
    sum += __shfl_xor(sum,32); ssq += __shfl_xor(ssq,32);
    __shared__ float ls[16];
    if (tid < 16) ls[tid] = 0.f;
    __syncthreads();
    int l = tid & 63;
    if ((l & 0x31) == 0){
      atomicAdd(&ls[l>>1], sum);
      atomicAdd(&ls[8 + (l>>1)], ssq);
    }
    __syncthreads();
    if (tid < 16) atomicAdd(&ws[O_SUM1 + tid], ls[tid]);
  }
}

// generic BN finalize: mean/var -> per-channel scale/shift
__global__ void k_fin(float* __restrict__ ws, const float* __restrict__ g,
                      const float* __restrict__ b, int count, float invM,
                      int o_sum, int o_ssq, int o_s, int o_t){
  int i = threadIdx.x;
  if (i >= count) return;
  float mean = ws[o_sum+i]*invM;
  float var  = ws[o_ssq+i]*invM - mean*mean;
  float s = g[i]*rsqrtf(var + kEPS);
  ws[o_s+i] = s;
  ws[o_t+i] = b[i] - mean*s;
}

// conv2 5x5 [N,8,11,11]->[N,10,7,7] + BN2 stats. Row-split: blocks <640 do
// conv rows 0..3, blocks >=640 do rows 4..6 (wave-uniform).
__global__ __launch_bounds__(256) void k_conv2(float* __restrict__ ws,
                                               const float* __restrict__ w2){
  const int blk = blockIdx.x;
  const int half = (blk >= 640) ? 1 : 0;
  const int gid = (blk - half*640)*256 + threadIdx.x;
  const int n = gid/10, oc = gid - 10*n;
  const int r0 = half*4;
  const float* __restrict__ inb = ws + O_POOL1 + n*968;
  float acc[28];
  #pragma unroll
  for (int i=0;i<28;i++) acc[i]=0.f;
  for (int ic=0; ic<8; ic++){
    const float* __restrict__ chan = inb + ic*121;
    const float* __restrict__ wch  = w2 + (oc*8+ic)*25;
    #pragma unroll
    for (int il=0; il<8; il++){
      if (half && il==7) continue;        // half1 needs only 7 input rows
      const int iy = r0 + il;
      float in[11];
      #pragma unroll
      for (int i=0;i<11;i++) in[i] = chan[iy*11+i];
      #pragma unroll
      for (int rl=0; rl<4; rl++){
        if (half && rl==3) continue;      // half1 owns only 3 conv rows
        const int ky = il - rl;
        if (ky >= 0 && ky < 5){           // compile-time (il, rl static)
          #pragma unroll
          for (int kx=0;kx<5;kx++){
            float wv = wch[ky*5+kx];
            #pragma unroll
            for (int xx=0;xx<7;xx++) acc[rl*7+xx] = fmaf(wv, in[xx+kx], acc[rl*7+xx]);
          }
        }
      }
    }
  }
  float sum=0.f, ssq=0.f;
  float* __restrict__ outp = ws + O_CONV2 + (n*10+oc)*49 + r0*7;
  const int NV = (half ? 3 : 4)*7;
  #pragma unroll
  for (int i=0;i<28;i++){
    if (i < NV){ float v = acc[i]; outp[i] = v; sum += v; ssq = fmaf(v,v,ssq); }
  }
  __shared__ float ls[20];
  if (threadIdx.x < 20) ls[threadIdx.x] = 0.f;
  __syncthreads();
  atomicAdd(&ls[oc], sum);
  atomicAdd(&ls[10+oc], ssq);
  __syncthreads();
  if (threadIdx.x < 20) atomicAdd(&ws[O_SUM2 + threadIdx.x], ls[threadIdx.x]);
}

// BN2 affine + 2x2 maxpool + relu -> pool2 [N,10,3,3]; also accumulate the
// 10-channel mean + covariance moments of pool2 (conv3 is 1x1 => BN3 stats
// derive analytically from these; no conv3 stats pass needed).
__global__ __launch_bounds__(256) void k_pool2mom(float* __restrict__ ws){
  __shared__ float smom[65];
  const int tid = threadIdx.x;
  if (tid < 65) smom[tid] = 0.f;
  __syncthreads();
  const int gid = blockIdx.x*256 + tid;
  const int n = gid/9, p = gid - 9*n;
  const int py = p/3, px = p - 3*py;
  const float* __restrict__ src = ws + O_CONV2 + n*490;
  float* __restrict__ outp = ws + O_POOL2 + n*90;
  float xv[10];
  #pragma unroll
  for (int oc=0; oc<10; oc++){
    float s = ws[O_S2+oc], t = ws[O_T2+oc];
    const float* cs = src + oc*49 + (2*py)*7 + 2*px;
    float v00 = cs[0], v01 = cs[1], v10 = cs[7], v11 = cs[8];
    float m4 = fmaxf(fmaxf(v00,v01), fmaxf(v10,v11));
    float n4 = fminf(fminf(v00,v01), fminf(v10,v11));
    float ext = (s >= 0.f) ? m4 : n4;
    float v = fmaxf(fmaf(s, ext, t), 0.f);
    xv[oc] = v;
    outp[oc*9 + p] = v;
  }
  float mu[10], sm[55];
  #pragma unroll
  for (int i=0;i<10;i++) mu[i] = xv[i];
  #pragma unroll
  for (int i=0;i<10;i++){
    #pragma unroll
    for (int j=i;j<10;j++) sm[i*10 - i*(i-1)/2 + (j-i)] = xv[i]*xv[j];
  }
  #pragma unroll
  for (int off=1; off<64; off<<=1){
    #pragma unroll
    for (int i=0;i<10;i++) mu[i] += __shfl_xor(mu[i], off);
    #pragma unroll
    for (int k=0;k<55;k++) sm[k] += __shfl_xor(sm[k], off);
  }
  if ((tid & 63) == 0){
    #pragma unroll
    for (int i=0;i<10;i++) atomicAdd(&smom[i], mu[i]);
    #pragma unroll
    for (int k=0;k<55;k++) atomicAdd(&smom[10+k], sm[k]);
  }
  __syncthreads();
  if (tid < 65) atomicAdd(&ws[O_MOM + tid], smom[tid]);
}

// BN3 finalize from pool2 moments: mean3 = w'mu, var3 = w'Cw (conv3 linear)
__global__ void k_fin3(float* __restrict__ ws, const float* __restrict__ w3,
                       const float* __restrict__ g3, const float* __restrict__ b3){
  const int oc = threadIdx.x;  // 128
  const float invM = 1.f/147456.f;
  float mu[10], w[10];
  #pragma unroll
  for (int i=0;i<10;i++) mu[i] = ws[O_MOM+i]*invM;
  #pragma unroll
  for (int i=0;i<10;i++) w[i] = w3[oc*10+i];
  float mean3 = 0.f;
  #pragma unroll
  for (int i=0;i<10;i++) mean3 += w[i]*mu[i];
  float var3 = 0.f;
  #pragma unroll
  for (int i=0;i<10;i++){
    #pragma unroll
    for (int j=i;j<10;j++){
      float Sij = ws[O_MOM+10 + i*10 - i*(i-1)/2 + (j-i)]*invM;
      float cov = Sij - mu[i]*mu[j];
      float coef = (i==j) ? 1.f : 2.f;
      var3 += coef * w[i] * w[j] * cov;
    }
  }
  var3 = fmaxf(var3, 0.f);
  float s = g3[oc]*rsqrtf(var3 + kEPS);
  ws[O_S3+oc] = s;
  ws[O_T3+oc] = b3[oc] - mean3*s;
}

// conv3(1x1) + BN3 + relu + avgpool(3x3) + fc -> theta[N,6]
__global__ __launch_bounds__(256) void k_theta(float* __restrict__ ws,
                                               const float* __restrict__ w3,
                                               const float* __restrict__ fw,
                                               const float* __restrict__ fb){
  const int n = blockIdx.x*256 + threadIdx.x;
  const float* __restrict__ ip = ws + O_POOL2 + n*90;
  float in[90];
  #pragma unroll
  for (int i=0;i<90;i++) in[i] = ip[i];
  float th[6];
  #pragma unroll
  for (int j=0;j<6;j++) th[j] = fb[j];
  for (int oc=0; oc<128; oc++){
    float s = ws[O_S3+oc], t = ws[O_T3+oc];
    float fsum = 0.f;
    #pragma unroll
    for (int p=0;p<9;p++){
      float v = 0.f;
      #pragma unroll
      for (int ic=0;ic<10;ic++) v = fmaf(w3[oc*10+ic], in[ic*9+p], v);
      fsum += fmaxf(fmaf(s,v,t), 0.f);
    }
    float feat = fsum * (1.f/9.f);
    #pragma unroll
    for (int j=0;j<6;j++) th[j] = fmaf(fw[j*128+oc], feat, th[j]);
  }
  float* __restrict__ op = ws + O_THETA + n*6;
  #pragma unroll
  for (int j=0;j<6;j++) op[j] = th[j];
}

// affine grid + bilinear sample; block <-> sample, image staged in LDS
__global__ __launch_bounds__(256) void k_sample(const float* __restrict__ x,
                                                const float* __restrict__ ws,
                                                float* __restrict__ out){
  const int n = blockIdx.x;
  __shared__ float sx[784];
  const int tid = threadIdx.x;
  if (tid < 196) ((float4*)sx)[tid] = ((const float4*)(x + n*784))[tid];
  __syncthreads();
  const float* __restrict__ th = ws + O_THETA + n*6;  // wave-uniform -> s_load
  const float t0=th[0], t1=th[1], t2=th[2], t3=th[3], t4=th[4], t5=th[5];
  float* __restrict__ op = out + n*784;
  for (int idx=tid; idx<784; idx+=256){
    int h = idx/28;
    int wcol = idx - 28*h;
    float gx = fmaf((float)wcol, 2.f/27.f, -1.f);
    float gy = fmaf((float)h,    2.f/27.f, -1.f);
    float ix = (fmaf(t0,gx,fmaf(t1,gy,t2)) + 1.f)*13.5f;
    float iy = (fmaf(t3,gx,fmaf(t4,gy,t5)) + 1.f)*13.5f;
    float x0f = floorf(ix), y0f = floorf(iy);
    float wx = ix - x0f, wy = iy - y0f;
    int x0 = min(max((int)x0f,0),27); int x1 = min(x0+1,27);
    int y0 = min(max((int)y0f,0),27); int y1 = min(y0+1,27);
    float v00 = sx[y0*28+x0], v01 = sx[y0*28+x1];
    float v10 = sx[y1*28+x0], v11 = sx[y1*28+x1];
    float top = v00*(1.f-wx) + v01*wx;
    float bot = v10*(1.f-wx) + v11*wx;
    op[idx] = top*(1.f-wy) + bot*wy;
  }
}

extern "C" void kernel_launch(void* const* d_in, const int* in_sizes, int n_in,
                              void* d_out, int out_size, void* d_ws, size_t ws_size,
                              hipStream_t stream){
  (void)in_sizes; (void)n_in; (void)out_size; (void)ws_size;
  const float* x  = (const float*)d_in[0];
  const float* w1 = (const float*)d_in[1];
  const float* g1 = (const float*)d_in[2];
  const float* b1 = (const float*)d_in[3];
  const float* w2 = (const float*)d_in[4];
  const float* g2 = (const float*)d_in[5];
  const float* b2 = (const float*)d_in[6];
  const float* w3 = (const float*)d_in[7];
  const float* g3 = (const float*)d_in[8];
  const float* b3 = (const float*)d_in[9];
  const float* fw = (const float*)d_in[10];
  const float* fb = (const float*)d_in[11];
  float* ws  = (float*)d_ws;
  float* out = (float*)d_out;

  hipLaunchKernelGGL(k_zero,       dim3(2),     dim3(256), 0, stream, ws);
  hipLaunchKernelGGL(k_conv1<0>,   dim3(1024),  dim3(256), 0, stream, x, w1, ws);
  hipLaunchKernelGGL(k_fin,        dim3(1),     dim3(64),  0, stream, ws, g1, b1, 8,  1.f/7929856.f, O_SUM1, O_SSQ1, O_S1, O_T1);
  hipLaunchKernelGGL(k_conv1<1>,   dim3(1024),  dim3(256), 0, stream, x, w1, ws);
  hipLaunchKernelGGL(k_conv2,      dim3(1280),  dim3(256), 0, stream, ws, w2);
  hipLaunchKernelGGL(k_fin,        dim3(1),     dim3(64),  0, stream, ws, g2, b2, 10, 1.f/802816.f,  O_SUM2, O_SSQ2, O_S2, O_T2);
  hipLaunchKernelGGL(k_pool2mom,   dim3(576),   dim3(256), 0, stream, ws);
  hipLaunchKernelGGL(k_fin3,       dim3(1),     dim3(128), 0, stream, ws, w3, g3, b3);
  hipLaunchKernelGGL(k_theta,      dim3(64),    dim3(256), 0, stream, ws, w3, fw, fb);
  hipLaunchKernelGGL(k_sample,     dim3(16384), dim3(256), 0, stream, x, ws, out);
}

// Round 2
// 568.165 us; speedup vs baseline: 1.0195x; 1.0195x over previous
//
#include <hip/hip_runtime.h>

// ---------------------------------------------------------------------------
// Spatial transformer loc-net + bilinear sampler. N=16384, x:[N,1,28,28] f32.
// R1: conv2 stage rebuilt — pool1 stored [N][11][11][8] (ic innermost),
//     w2 pre-transposed to [oc][ky][kx][ic], conv2 two-pass (stats / BN+pool)
//     so the 32MB conv2 map is never materialized.
// ---------------------------------------------------------------------------

static constexpr float kEPS = 1e-5f;

// ws float offsets
#define O_SUM1 0
#define O_SSQ1 8
#define O_SUM2 16
#define O_SSQ2 26
#define O_MOM  36      // 10 means + 55 upper-tri second moments of pool2
#define O_S1   104
#define O_T1   112
#define O_S2   120
#define O_T2   130
#define O_S3   140
#define O_T3   268
#define O_W2T  400             // 2000 floats: w2 as [oc][ky][kx][ic]
#define O_THETA 2432           // 16384*6
#define O_POOL1 100864         // [N][11][11][8] interleaved, 15,859,712 floats
#define O_POOL2 15960576       // [N][9][10]  (p outer, ic inner) 1,474,560
// total ws use ≈ 69.7 MB

__global__ __launch_bounds__(256) void k_zero(float* __restrict__ ws){
  int i = blockIdx.x*256 + threadIdx.x;
  if (i < 512) ws[i] = 0.f;
}

// transpose w2 [10][8][5][5] -> [oc][ky][kx][ic] (2000 floats)
__global__ __launch_bounds__(256) void k_prep(const float* __restrict__ w2,
                                              float* __restrict__ ws){
  int i = blockIdx.x*256 + threadIdx.x;
  if (i >= 2000) return;
  int ic = i & 7;
  int r  = i >> 3;
  int kx = r % 5; r /= 5;
  int ky = r % 5; r /= 5;
  int oc = r;
  ws[O_W2T + i] = w2[(oc*8 + ic)*25 + ky*5 + kx];
}

// conv1 7x7 [N,1,28,28]->[N,8,22,22]. PASS0: BN stats. PASS1: BN affine +
// 2x2 maxpool + relu -> pool1 [N][11][11][8].
template<int PASS>
__global__ __launch_bounds__(256) void k_conv1(const float* __restrict__ x,
                                               const float* __restrict__ w1,
                                               float* __restrict__ ws){
  const int tid = threadIdx.x;
  const int gid = blockIdx.x*256 + tid;
  const int ph = gid & 1;          // which half of the 11 pooled rows
  const int c  = (gid >> 1) & 7;
  const int n  = gid >> 4;
  const float* __restrict__ xs = x + n*784;
  float w[49];
  #pragma unroll
  for (int i=0;i<49;i++) w[i] = w1[c*49+i];
  float sbn = 0.f, tbn = 0.f;
  if (PASS==1){ sbn = ws[O_S1+c]; tbn = ws[O_T1+c]; }
  float sum=0.f, ssq=0.f;
  float* __restrict__ outp = ws + O_POOL1 + n*968 + c;   // interleaved base
  const int p0 = ph*6;
  const int p1 = ph ? 11 : 6;
  for (int p=p0; p<p1; p++){
    float a0[22], a1[22];
    #pragma unroll
    for (int i=0;i<22;i++){ a0[i]=0.f; a1[i]=0.f; }
    #pragma unroll
    for (int j=0;j<8;j++){            // input rows 2p..2p+7 feed conv rows 2p,2p+1
      float in[28];
      const float4* __restrict__ rp = (const float4*)(xs + (2*p+j)*28);
      #pragma unroll
      for (int q=0;q<7;q++){
        float4 v = rp[q];
        in[4*q]=v.x; in[4*q+1]=v.y; in[4*q+2]=v.z; in[4*q+3]=v.w;
      }
      if (j < 7){                     // ky = j for conv row 2p
        #pragma unroll
        for (int kx=0;kx<7;kx++){
          float wv = w[j*7+kx];
          #pragma unroll
          for (int xo=0;xo<22;xo++) a0[xo] = fmaf(wv, in[xo+kx], a0[xo]);
        }
      }
      if (j >= 1){                    // ky = j-1 for conv row 2p+1
        #pragma unroll
        for (int kx=0;kx<7;kx++){
          float wv = w[(j-1)*7+kx];
          #pragma unroll
          for (int xo=0;xo<22;xo++) a1[xo] = fmaf(wv, in[xo+kx], a1[xo]);
        }
      }
    }
    if (PASS==0){
      #pragma unroll
      for (int xo=0;xo<22;xo++){
        sum += a0[xo] + a1[xo];
        ssq = fmaf(a0[xo],a0[xo],ssq);
        ssq = fmaf(a1[xo],a1[xo],ssq);
      }
    } else {
      #pragma unroll
      for (int px=0;px<11;px++){
        float m4 = fmaxf(fmaxf(a0[2*px],a0[2*px+1]), fmaxf(a1[2*px],a1[2*px+1]));
        float n4 = fminf(fminf(a0[2*px],a0[2*px+1]), fminf(a1[2*px],a1[2*px+1]));
        float ext = (sbn >= 0.f) ? m4 : n4;  // maxpool after affine: sign-aware
        outp[(p*11+px)*8] = fmaxf(fmaf(sbn, ext, tbn), 0.f);
      }
    }
  }
  if (PASS==0){
    // lanes sharing c differ in bits {0,4,5} of lane id
    sum += __shfl_xor(sum,1);  ssq += __shfl_xor(ssq,1);
    sum += __shfl_xor(sum,16); ssq += __shfl_xor(ssq,16);
    sum += __shfl_xor(sum,32); ssq += __shfl_xor(ssq,32);
    __shared__ float ls[16];
    if (tid < 16) ls[tid] = 0.f;
    __syncthreads();
    int l = tid & 63;
    if ((l & 0x31) == 0){
      atomicAdd(&ls[l>>1], sum);
      atomicAdd(&ls[8 + (l>>1)], ssq);
    }
    __syncthreads();
    if (tid < 16) atomicAdd(&ws[O_SUM1 + tid], ls[tid]);
  }
}

// generic BN finalize: mean/var -> per-channel scale/shift
__global__ void k_fin(float* __restrict__ ws, const float* __restrict__ g,
                      const float* __restrict__ b, int count, float invM,
                      int o_sum, int o_ssq, int o_s, int o_t){
  int i = threadIdx.x;
  if (i >= count) return;
  float mean = ws[o_sum+i]*invM;
  float var  = ws[o_ssq+i]*invM - mean*mean;
  float s = g[i]*rsqrtf(var + kEPS);
  ws[o_s+i] = s;
  ws[o_t+i] = b[i] - mean*s;
}

// conv2 5x5 [N,8,11,11]->[N,10,7,7] from interleaved pool1.
// PASS0: BN2 stats over the full 7x7 map. PASS1: BN affine + 2x2 maxpool +
// relu -> pool2 [N][9][10]. Row-split: blocks<640 own conv rows 0..3,
// blocks>=640 own rows 4..6 (wave-uniform).
template<int PASS>
__global__ __launch_bounds__(256) void k_conv2(float* __restrict__ ws){
  const int blk = blockIdx.x;
  const int half = (blk >= 640) ? 1 : 0;
  const int gid = (blk - half*640)*256 + threadIdx.x;
  const int n = gid/10, oc = gid - 10*n;
  const int r0 = half*4;                 // first owned conv row
  const int nrows = half ? 7 : 8;        // input rows streamed
  const float* __restrict__ wt = ws + O_W2T + oc*200;
  const float* __restrict__ base = ws + O_POOL1 + n*968;
  float acc[28];
  #pragma unroll
  for (int i=0;i<28;i++) acc[i]=0.f;
  for (int jj=0; jj<nrows; ++jj){        // uniform loop
    const int iy = r0 + jj;
    float in[88];
    const float4* __restrict__ rp = (const float4*)(base + iy*88);
    #pragma unroll
    for (int q=0;q<22;q++){
      float4 v = rp[q];
      in[4*q]=v.x; in[4*q+1]=v.y; in[4*q+2]=v.z; in[4*q+3]=v.w;
    }
    #pragma unroll
    for (int ol=0; ol<4; ++ol){          // owned conv row (local)
      if (half && ol==3) continue;       // half1 owns 3 rows
      const int ky = jj - ol;            // uniform at runtime
      if (ky < 0 || ky > 4) continue;
      const float* __restrict__ wrow = wt + ky*40;
      #pragma unroll
      for (int kx=0;kx<5;kx++){
        float4 wa = *(const float4*)(wrow + kx*8);
        float4 wb = *(const float4*)(wrow + kx*8 + 4);
        #pragma unroll
        for (int ox=0;ox<7;ox++){
          float a = acc[ol*7+ox];
          a = fmaf(wa.x, in[(ox+kx)*8+0], a);
          a = fmaf(wa.y, in[(ox+kx)*8+1], a);
          a = fmaf(wa.z, in[(ox+kx)*8+2], a);
          a = fmaf(wa.w, in[(ox+kx)*8+3], a);
          a = fmaf(wb.x, in[(ox+kx)*8+4], a);
          a = fmaf(wb.y, in[(ox+kx)*8+5], a);
          a = fmaf(wb.z, in[(ox+kx)*8+6], a);
          a = fmaf(wb.w, in[(ox+kx)*8+7], a);
          acc[ol*7+ox] = a;
        }
      }
    }
  }
  if (PASS==0){
    const int NV = (half ? 3 : 4)*7;
    float sum=0.f, ssq=0.f;
    #pragma unroll
    for (int i=0;i<28;i++){
      if (i < NV){ float v = acc[i]; sum += v; ssq = fmaf(v,v,ssq); }
    }
    __shared__ float ls[20];
    if (threadIdx.x < 20) ls[threadIdx.x] = 0.f;
    __syncthreads();
    atomicAdd(&ls[oc], sum);
    atomicAdd(&ls[10+oc], ssq);
    __syncthreads();
    if (threadIdx.x < 20) atomicAdd(&ws[O_SUM2 + threadIdx.x], ls[threadIdx.x]);
  } else {
    const float s = ws[O_S2+oc], t = ws[O_T2+oc];
    // pooled rows owned: half0 -> py 0,1 (conv rows 0-3); half1 -> py 2 (rows 4,5)
    const int npy = half ? 1 : 2;
    #pragma unroll
    for (int pl=0; pl<2; pl++){
      if (pl >= npy) continue;
      const int py = half ? 2 : pl;
      #pragma unroll
      for (int px=0;px<3;px++){
        float v00 = acc[(2*pl)*7   + 2*px], v01 = acc[(2*pl)*7   + 2*px+1];
        float v10 = acc[(2*pl+1)*7 + 2*px], v11 = acc[(2*pl+1)*7 + 2*px+1];
        float m4 = fmaxf(fmaxf(v00,v01), fmaxf(v10,v11));
        float n4 = fminf(fminf(v00,v01), fminf(v10,v11));
        float ext = (s >= 0.f) ? m4 : n4;
        ws[O_POOL2 + (n*9 + py*3 + px)*10 + oc] = fmaxf(fmaf(s, ext, t), 0.f);
      }
    }
  }
}

// pool2 [N][9][10] -> 10 means + 55 second moments (for analytic BN3 stats)
__global__ __launch_bounds__(256) void k_pool2mom(float* __restrict__ ws){
  __shared__ float smom[65];
  const int tid = threadIdx.x;
  if (tid < 65) smom[tid] = 0.f;
  __syncthreads();
  const int gid = blockIdx.x*256 + tid;       // 147456 = N*9
  const float* __restrict__ p = ws + O_POOL2 + gid*10;
  float xv[10];
  #pragma unroll
  for (int i=0;i<10;i++) xv[i] = p[i];
  float mu[10], sm[55];
  #pragma unroll
  for (int i=0;i<10;i++) mu[i] = xv[i];
  #pragma unroll
  for (int i=0;i<10;i++){
    #pragma unroll
    for (int j=i;j<10;j++) sm[i*10 - i*(i-1)/2 + (j-i)] = xv[i]*xv[j];
  }
  #pragma unroll
  for (int off=1; off<64; off<<=1){
    #pragma unroll
    for (int i=0;i<10;i++) mu[i] += __shfl_xor(mu[i], off);
    #pragma unroll
    for (int k=0;k<55;k++) sm[k] += __shfl_xor(sm[k], off);
  }
  if ((tid & 63) == 0){
    #pragma unroll
    for (int i=0;i<10;i++) atomicAdd(&smom[i], mu[i]);
    #pragma unroll
    for (int k=0;k<55;k++) atomicAdd(&smom[10+k], sm[k]);
  }
  __syncthreads();
  if (tid < 65) atomicAdd(&ws[O_MOM + tid], smom[tid]);
}

// BN3 finalize from pool2 moments: mean3 = w'mu, var3 = w'Cw (conv3 linear)
__global__ void k_fin3(float* __restrict__ ws, const float* __restrict__ w3,
                       const float* __restrict__ g3, const float* __restrict__ b3){
  const int oc = threadIdx.x;  // 128
  const float invM = 1.f/147456.f;
  float mu[10], w[10];
  #pragma unroll
  for (int i=0;i<10;i++) mu[i] = ws[O_MOM+i]*invM;
  #pragma unroll
  for (int i=0;i<10;i++) w[i] = w3[oc*10+i];
  float mean3 = 0.f;
  #pragma unroll
  for (int i=0;i<10;i++) mean3 += w[i]*mu[i];
  float var3 = 0.f;
  #pragma unroll
  for (int i=0;i<10;i++){
    #pragma unroll
    for (int j=i;j<10;j++){
      float Sij = ws[O_MOM+10 + i*10 - i*(i-1)/2 + (j-i)]*invM;
      float cov = Sij - mu[i]*mu[j];
      float coef = (i==j) ? 1.f : 2.f;
      var3 += coef * w[i] * w[j] * cov;
    }
  }
  var3 = fmaxf(var3, 0.f);
  float s = g3[oc]*rsqrtf(var3 + kEPS);
  ws[O_S3+oc] = s;
  ws[O_T3+oc] = b3[oc] - mean3*s;
}

// conv3(1x1) + BN3 + relu + avgpool(3x3) + fc -> theta[N,6]
__global__ __launch_bounds__(256) void k_theta(float* __restrict__ ws,
                                               const float* __restrict__ w3,
                                               const float* __restrict__ fw,
                                               const float* __restrict__ fb){
  const int n = blockIdx.x*256 + threadIdx.x;
  const float* __restrict__ ip = ws + O_POOL2 + n*90;   // [9 p][10 ic]
  float in[90];
  #pragma unroll
  for (int i=0;i<90;i++) in[i] = ip[i];
  float th[6];
  #pragma unroll
  for (int j=0;j<6;j++) th[j] = fb[j];
  for (int oc=0; oc<128; oc++){
    float s = ws[O_S3+oc], t = ws[O_T3+oc];
    float fsum = 0.f;
    #pragma unroll
    for (int p=0;p<9;p++){
      float v = 0.f;
      #pragma unroll
      for (int ic=0;ic<10;ic++) v = fmaf(w3[oc*10+ic], in[p*10+ic], v);
      fsum += fmaxf(fmaf(s,v,t), 0.f);
    }
    float feat = fsum * (1.f/9.f);
    #pragma unroll
    for (int j=0;j<6;j++) th[j] = fmaf(fw[j*128+oc], feat, th[j]);
  }
  float* __restrict__ op = ws + O_THETA + n*6;
  #pragma unroll
  for (int j=0;j<6;j++) op[j] = th[j];
}

// affine grid + bilinear sample; block <-> sample, image staged in LDS
__global__ __launch_bounds__(256) void k_sample(const float* __restrict__ x,
                                                const float* __restrict__ ws,
                                                float* __restrict__ out){
  const int n = blockIdx.x;
  __shared__ float sx[784];
  const int tid = threadIdx.x;
  if (tid < 196) ((float4*)sx)[tid] = ((const float4*)(x + n*784))[tid];
  __syncthreads();
  const float* __restrict__ th = ws + O_THETA + n*6;  // wave-uniform -> s_load
  const float t0=th[0], t1=th[1], t2=th[2], t3=th[3], t4=th[4], t5=th[5];
  float* __restrict__ op = out + n*784;
  for (int idx=tid; idx<784; idx+=256){
    int h = idx/28;
    int wcol = idx - 28*h;
    float gx = fmaf((float)wcol, 2.f/27.f, -1.f);
    float gy = fmaf((float)h,    2.f/27.f, -1.f);
    float ix = (fmaf(t0,gx,fmaf(t1,gy,t2)) + 1.f)*13.5f;
    float iy = (fmaf(t3,gx,fmaf(t4,gy,t5)) + 1.f)*13.5f;
    float x0f = floorf(ix), y0f = floorf(iy);
    float wx = ix - x0f, wy = iy - y0f;
    int x0 = min(max((int)x0f,0),27); int x1 = min(x0+1,27);
    int y0 = min(max((int)y0f,0),27); int y1 = min(y0+1,27);
    float v00 = sx[y0*28+x0], v01 = sx[y0*28+x1];
    float v10 = sx[y1*28+x0], v11 = sx[y1*28+x1];
    float top = v00*(1.f-wx) + v01*wx;
    float bot = v10*(1.f-wx) + v11*wx;
    op[idx] = top*(1.f-wy) + bot*wy;
  }
}

extern "C" void kernel_launch(void* const* d_in, const int* in_sizes, int n_in,
                              void* d_out, int out_size, void* d_ws, size_t ws_size,
                              hipStream_t stream){
  (void)in_sizes; (void)n_in; (void)out_size; (void)ws_size;
  const float* x  = (const float*)d_in[0];
  const float* w1 = (const float*)d_in[1];
  const float* g1 = (const float*)d_in[2];
  const float* b1 = (const float*)d_in[3];
  const float* w2 = (const float*)d_in[4];
  const float* g2 = (const float*)d_in[5];
  const float* b2 = (const float*)d_in[6];
  const float* w3 = (const float*)d_in[7];
  const float* g3 = (const float*)d_in[8];
  const float* b3 = (const float*)d_in[9];
  const float* fw = (const float*)d_in[10];
  const float* fb = (const float*)d_in[11];
  float* ws  = (float*)d_ws;
  float* out = (float*)d_out;

  hipLaunchKernelGGL(k_zero,       dim3(2),     dim3(256), 0, stream, ws);
  hipLaunchKernelGGL(k_prep,       dim3(8),     dim3(256), 0, stream, w2, ws);
  hipLaunchKernelGGL(k_conv1<0>,   dim3(1024),  dim3(256), 0, stream, x, w1, ws);
  hipLaunchKernelGGL(k_fin,        dim3(1),     dim3(64),  0, stream, ws, g1, b1, 8,  1.f/7929856.f, O_SUM1, O_SSQ1, O_S1, O_T1);
  hipLaunchKernelGGL(k_conv1<1>,   dim3(1024),  dim3(256), 0, stream, x, w1, ws);
  hipLaunchKernelGGL(k_conv2<0>,   dim3(1280),  dim3(256), 0, stream, ws);
  hipLaunchKernelGGL(k_fin,        dim3(1),     dim3(64),  0, stream, ws, g2, b2, 10, 1.f/802816.f,  O_SUM2, O_SSQ2, O_S2, O_T2);
  hipLaunchKernelGGL(k_conv2<1>,   dim3(1280),  dim3(256), 0, stream, ws);
  hipLaunchKernelGGL(k_pool2mom,   dim3(576),   dim3(256), 0, stream, ws);
  hipLaunchKernelGGL(k_fin3,       dim3(1),     dim3(128), 0, stream, ws, w3, g3, b3);
  hipLaunchKernelGGL(k_theta,      dim3(64),    dim3(256), 0, stream, ws, w3, fw, fb);
  hipLaunchKernelGGL(k_sample,     dim3(16384), dim3(256), 0, stream, x, ws, out);
}